// Round 1
// baseline (1259.754 us; speedup 1.0000x reference)
//
#include <hip/hip_runtime.h>
#include <math.h>

#define N_NODES 100000
#define N_EDGES 3200000
#define DIM_IN 128
#define HL 32
#define DIM_OUT 40
#define BN_EPS 1e-5f

// ---------------- Wc = W @ c1_W1  (128x128 @ 128x32) ----------------
__global__ __launch_bounds__(256) void k_wc(const float* __restrict__ W,
                                            const float* __restrict__ W1,
                                            float* __restrict__ Wc) {
    int idx = blockIdx.x * 256 + threadIdx.x;   // 0..4095
    int i = idx >> 5;   // 0..127
    int j = idx & 31;   // 0..31
    float acc = 0.f;
    for (int k = 0; k < DIM_IN; ++k) acc += W[i * DIM_IN + k] * W1[k * HL + j];
    Wc[i * HL + j] = acc;
}

// ---------------- u = x @ Wc  ([N,128] @ [128,32]) ----------------
__global__ __launch_bounds__(256) void k_xproj(const float* __restrict__ x,
                                               const float* __restrict__ Wc,
                                               float* __restrict__ u) {
    __shared__ float Ws[DIM_IN * HL];   // 16 KB
    __shared__ float xs[8][DIM_IN];     // 4 KB
    int t = threadIdx.x;
    for (int i = t; i < DIM_IN * HL; i += 256) Ws[i] = Wc[i];
    int base = blockIdx.x * 8;
    for (int i = t; i < 8 * DIM_IN; i += 256) {
        int r = i >> 7;
        if (base + r < N_NODES) xs[r][i & 127] = x[base * DIM_IN + i];
    }
    __syncthreads();
    int slot = t >> 5, d = t & 31;
    int node = base + slot;
    if (node < N_NODES) {
        float acc = 0.f;
        #pragma unroll 4
        for (int k = 0; k < DIM_IN; ++k) acc += xs[slot][k] * Ws[k * HL + d];
        u[node * HL + d] = acc;
    }
}

// ---------------- CSR build ----------------
__global__ void k_count(const int* __restrict__ dst, int* __restrict__ deg) {
    int e = blockIdx.x * 256 + threadIdx.x;
    if (e < N_EDGES) atomicAdd(&deg[dst[e]], 1);
}

__global__ __launch_bounds__(256) void k_scan1(const int* __restrict__ deg,
                                               int* __restrict__ row_ptr,
                                               int* __restrict__ bsums) {
    __shared__ int s[256];
    int t = threadIdx.x;
    int i = blockIdx.x * 256 + t;
    int val = (i < N_NODES) ? deg[i] : 0;
    s[t] = val;
    __syncthreads();
    for (int off = 1; off < 256; off <<= 1) {
        int a = 0;
        if (t >= off) a = s[t - off];
        __syncthreads();
        s[t] += a;
        __syncthreads();
    }
    if (i < N_NODES) row_ptr[i] = s[t] - val;   // exclusive within block
    if (t == 255) bsums[blockIdx.x] = s[255];
}

__global__ __launch_bounds__(512) void k_scan2(const int* __restrict__ bsums,
                                               int* __restrict__ boffs, int nb) {
    __shared__ int s[512];
    int t = threadIdx.x;
    int val = (t < nb) ? bsums[t] : 0;
    s[t] = val;
    __syncthreads();
    for (int off = 1; off < 512; off <<= 1) {
        int a = 0;
        if (t >= off) a = s[t - off];
        __syncthreads();
        s[t] += a;
        __syncthreads();
    }
    if (t < nb) boffs[t] = s[t] - val;   // exclusive
}

__global__ void k_scan3(int* __restrict__ row_ptr, const int* __restrict__ boffs,
                        int* __restrict__ cursor) {
    int i = blockIdx.x * 256 + threadIdx.x;
    if (i < N_NODES) {
        int v = row_ptr[i] + boffs[i >> 8];
        row_ptr[i] = v;
        cursor[i] = v;
    }
    if (i == 0) row_ptr[N_NODES] = N_EDGES;
}

__global__ void k_scatter(const int* __restrict__ src, const int* __restrict__ dst,
                          int* __restrict__ cursor, int* __restrict__ srcs) {
    int e = blockIdx.x * 256 + threadIdx.x;
    if (e < N_EDGES) {
        int p = atomicAdd(&cursor[dst[e]], 1);
        srcs[p] = src[e];
    }
}

// ---------------- fused conv: agg + b1 + BN + ReLU + @W2 + b2 + ReLU ----------------
__global__ __launch_bounds__(256) void k_conv(const float* __restrict__ u,
                                              const int* __restrict__ row_ptr,
                                              const int* __restrict__ srcs,
                                              const float* __restrict__ b1,
                                              const float* __restrict__ g,
                                              const float* __restrict__ be,
                                              const float* __restrict__ m,
                                              const float* __restrict__ v,
                                              const float* __restrict__ W2,
                                              const float* __restrict__ b2,
                                              float* __restrict__ hcat, int col_off) {
    __shared__ float W2s[HL * HL];     // 4 KB
    __shared__ float ts[8][HL + 1];
    int t = threadIdx.x;
    for (int i = t; i < HL * HL; i += 256) W2s[i] = W2[i];
    int slot = t >> 5, d = t & 31;
    int node = blockIdx.x * 8 + slot;
    float acc = 0.f;
    if (node < N_NODES) {
        acc = u[node * HL + d];
        int e0 = row_ptr[node], e1 = row_ptr[node + 1];
        int e = e0;
        for (; e + 4 <= e1; e += 4) {
            int s0 = srcs[e], s1 = srcs[e + 1], s2 = srcs[e + 2], s3 = srcs[e + 3];
            float a0 = u[s0 * HL + d];
            float a1 = u[s1 * HL + d];
            float a2 = u[s2 * HL + d];
            float a3 = u[s3 * HL + d];
            acc += a0 + a1 + a2 + a3;
        }
        for (; e < e1; ++e) acc += u[srcs[e] * HL + d];
        acc += b1[d];
        acc = (acc - m[d]) * (g[d] * rsqrtf(v[d] + BN_EPS)) + be[d];
        acc = fmaxf(acc, 0.f);
    }
    ts[slot][d] = acc;
    __syncthreads();
    if (node < N_NODES) {
        float h = b2[d];
        #pragma unroll
        for (int k = 0; k < HL; ++k) h += ts[slot][k] * W2s[k * HL + d];
        h = fmaxf(h, 0.f);
        hcat[node * DIM_IN + col_off + d] = h;
    }
}

// ---------------- u = h_prev @ W1  ([N,32] @ [32,32], h_prev strided in hcat) ----------------
__global__ __launch_bounds__(256) void k_proj(const float* __restrict__ hcat, int col_off,
                                              const float* __restrict__ W1,
                                              float* __restrict__ u) {
    __shared__ float Ws[HL * HL];
    __shared__ float hs[8][HL + 1];
    int t = threadIdx.x;
    for (int i = t; i < HL * HL; i += 256) Ws[i] = W1[i];
    int slot = t >> 5, d = t & 31;
    int node = blockIdx.x * 8 + slot;
    float hv = 0.f;
    if (node < N_NODES) hv = hcat[node * DIM_IN + col_off + d];
    hs[slot][d] = hv;
    __syncthreads();
    if (node < N_NODES) {
        float acc = 0.f;
        #pragma unroll
        for (int k = 0; k < HL; ++k) acc += hs[slot][k] * Ws[k * HL + d];
        u[node * HL + d] = acc;
    }
}

// ---------------- final: lin1 + ReLU + lin2 + log_softmax ----------------
__global__ __launch_bounds__(256) void k_final(const float* __restrict__ hcat,
                                               const float* __restrict__ W1,
                                               const float* __restrict__ b1,
                                               const float* __restrict__ W2,
                                               const float* __restrict__ b2,
                                               float* __restrict__ out) {
    __shared__ float rows[2][DIM_IN];
    __shared__ float tt[2][DIM_IN];
    int t = threadIdx.x;
    int slot = t >> 7;        // 0..1
    int i = t & 127;
    int node = blockIdx.x * 2 + slot;
    if (node < N_NODES) rows[slot][i] = hcat[node * DIM_IN + i];
    __syncthreads();
    float acc = b1[i];
    if (node < N_NODES) {
        #pragma unroll 4
        for (int k = 0; k < DIM_IN; ++k) acc += rows[slot][k] * W1[k * DIM_IN + i];
    }
    tt[slot][i] = fmaxf(acc, 0.f);
    __syncthreads();
    // lin2 + log_softmax: waves 0 and 2 handle node slot 0/1 respectively
    if ((t & 64) == 0) {
        int lane = t & 63;
        float o = -INFINITY;
        if (node < N_NODES && lane < DIM_OUT) {
            o = b2[lane];
            #pragma unroll 4
            for (int k = 0; k < DIM_IN; ++k) o += tt[slot][k] * W2[k * DIM_OUT + lane];
        }
        float mx = o;
        for (int off = 32; off >= 1; off >>= 1) mx = fmaxf(mx, __shfl_xor(mx, off, 64));
        float ex = (node < N_NODES && lane < DIM_OUT) ? expf(o - mx) : 0.f;
        float sm = ex;
        for (int off = 32; off >= 1; off >>= 1) sm += __shfl_xor(sm, off, 64);
        if (node < N_NODES && lane < DIM_OUT) {
            out[node * DIM_OUT + lane] = o;
            out[(size_t)N_NODES * DIM_OUT + node * DIM_OUT + lane] = o - mx - logf(sm);
        }
    }
}

extern "C" void kernel_launch(void* const* d_in, const int* in_sizes, int n_in,
                              void* d_out, int out_size, void* d_ws, size_t ws_size,
                              hipStream_t stream) {
    const float* x      = (const float*)d_in[0];
    const int*   ei     = (const int*)d_in[1];
    const float* W      = (const float*)d_in[2];
    const float* c1_W1  = (const float*)d_in[3];
    const float* c1_b1  = (const float*)d_in[4];
    const float* c1_g   = (const float*)d_in[5];
    const float* c1_be  = (const float*)d_in[6];
    const float* c1_m   = (const float*)d_in[7];
    const float* c1_v   = (const float*)d_in[8];
    const float* c1_W2  = (const float*)d_in[9];
    const float* c1_b2  = (const float*)d_in[10];
    const float* cW1    = (const float*)d_in[11];
    const float* cb1    = (const float*)d_in[12];
    const float* cg     = (const float*)d_in[13];
    const float* cbe    = (const float*)d_in[14];
    const float* cm     = (const float*)d_in[15];
    const float* cv     = (const float*)d_in[16];
    const float* cW2    = (const float*)d_in[17];
    const float* cb2    = (const float*)d_in[18];
    const float* lin1_W = (const float*)d_in[19];
    const float* lin1_b = (const float*)d_in[20];
    const float* lin2_W = (const float*)d_in[21];
    const float* lin2_b = (const float*)d_in[22];

    const int* esrc = ei;
    const int* edst = ei + N_EDGES;

    // workspace carve (all 4B aligned); total ~78 MB
    float* u       = (float*)d_ws;                       // N*32
    float* hcat    = u + (size_t)N_NODES * HL;           // N*128
    float* Wc      = hcat + (size_t)N_NODES * DIM_IN;    // 128*32
    int*   row_ptr = (int*)(Wc + DIM_IN * HL);           // N+1
    int*   cursor  = row_ptr + (N_NODES + 1);            // N (also deg)
    int*   srcs    = cursor + N_NODES;                   // E
    int*   bsums   = srcs + N_EDGES;                     // 512
    int*   boffs   = bsums + 512;                        // 512

    const int NB_NODE = (N_NODES + 255) / 256;   // 391
    const int NB_EDGE = (N_EDGES + 255) / 256;
    const int NB_CONV = (N_NODES + 7) / 8;       // 12500

    hipMemsetAsync(cursor, 0, N_NODES * sizeof(int), stream);
    k_wc<<<16, 256, 0, stream>>>(W, c1_W1, Wc);
    k_xproj<<<NB_CONV, 256, 0, stream>>>(x, Wc, u);

    // CSR build (reused by all 4 convs)
    k_count<<<NB_EDGE, 256, 0, stream>>>(edst, cursor);
    k_scan1<<<NB_NODE, 256, 0, stream>>>(cursor, row_ptr, bsums);
    k_scan2<<<1, 512, 0, stream>>>(bsums, boffs, NB_NODE);
    k_scan3<<<NB_NODE, 256, 0, stream>>>(row_ptr, boffs, cursor);
    k_scatter<<<NB_EDGE, 256, 0, stream>>>(esrc, edst, cursor, srcs);

    // conv1 (W1 pre-folded into u)
    k_conv<<<NB_CONV, 256, 0, stream>>>(u, row_ptr, srcs, c1_b1, c1_g, c1_be, c1_m,
                                        c1_v, c1_W2, c1_b2, hcat, 0);
    // conv2..conv4
    for (int i = 0; i < 3; ++i) {
        k_proj<<<NB_CONV, 256, 0, stream>>>(hcat, i * HL, cW1 + i * HL * HL, u);
        k_conv<<<NB_CONV, 256, 0, stream>>>(u, row_ptr, srcs, cb1 + i * HL, cg + i * HL,
                                            cbe + i * HL, cm + i * HL, cv + i * HL,
                                            cW2 + i * HL * HL, cb2 + i * HL, hcat,
                                            (i + 1) * HL);
    }

    k_final<<<(N_NODES + 1) / 2, 256, 0, stream>>>(hcat, lin1_W, lin1_b, lin2_W,
                                                   lin2_b, (float*)d_out);
}